// Round 1
// baseline (316.050 us; speedup 1.0000x reference)
//
#include <hip/hip_runtime.h>
#include <cmath>

constexpr int      kLevels   = 12;
constexpr unsigned kHashSize = 1u << 19;            // 524288
constexpr unsigned kHashMask = kHashSize - 1u;
constexpr int      kPoints   = 1 << 21;             // 2,097,152

struct ResArr { float r[kLevels]; };

__global__ __launch_bounds__(256) void hash_embed_kernel(
    const float*  __restrict__ x,     // [N,3] f32
    const float2* __restrict__ emb,   // [L, 2^19] of float2
    float2*       __restrict__ out,   // [N, 12] of float2  (== [N,24] f32)
    ResArr res)
{
    unsigned tid = blockIdx.x * 256u + threadIdx.x;   // tid = n*12 + l
    unsigned n   = tid / (unsigned)kLevels;
    unsigned l   = tid - n * (unsigned)kLevels;

    // per-lane level -> resolution (12-deep cndmask chain, values live in SGPRs)
    float r = res.r[0];
#pragma unroll
    for (int i = 1; i < kLevels; ++i) {
        r = (l == (unsigned)i) ? res.r[i] : r;
    }

    // 12 consecutive lanes read the same point -> L1 broadcast
    float px = x[n * 3u + 0u];
    float py = x[n * 3u + 1u];
    float pz = x[n * 3u + 2u];

    // exact IEEE f32 multiply + floor, identical to the reference
    unsigned x0 = (unsigned)floorf(px * r);
    unsigned y0 = (unsigned)floorf(py * r);
    unsigned z0 = (unsigned)floorf(pz * r);

    unsigned h = (x0 ^ (y0 * 2654435761u) ^ (z0 * 805459861u)) & kHashMask;

    float2 e = emb[l * kHashSize + h];

    // out float-offset = 24*n + 2*l = 2*tid  ->  one contiguous u64 stream.
    // Nontemporal: don't let the 201 MB write stream evict the tables from L2.
    unsigned long long v;
    __builtin_memcpy(&v, &e, sizeof(v));
    __builtin_nontemporal_store(v, reinterpret_cast<unsigned long long*>(out) + tid);
}

extern "C" void kernel_launch(void* const* d_in, const int* in_sizes, int n_in,
                              void* d_out, int out_size, void* d_ws, size_t ws_size,
                              hipStream_t stream) {
    const float*  x   = (const float*)d_in[0];
    const float2* emb = (const float2*)d_in[1];
    float2*       out = (float2*)d_out;

    // Replicate the reference's float64 resolution computation exactly
    // (same libm call sequence: log, sub, div, exp, pow, truncating int cast).
    ResArr res;
    const double growth = std::exp((std::log(512.0) - std::log(16.0)) / 11.0);
    for (int i = 0; i < kLevels; ++i) {
        res.r[i] = (float)(int)(16.0 * std::pow(growth, (double)i));
    }

    const int total = kPoints * kLevels;   // 25,165,824 (divisible by 256)
    const int block = 256;
    const int grid  = total / block;       // 98,304 blocks
    hipLaunchKernelGGL(hash_embed_kernel, dim3(grid), dim3(block), 0, stream,
                       x, emb, out, res);
}